// Round 19
// baseline (207.767 us; speedup 1.0000x reference)
//
#include <hip/hip_runtime.h>
#include <hip/hip_bf16.h>

// VectorQuantiser: x [32,64,64,64] f32, embeddings [64,1024] f32.
// argmin_k ||z - e_k||^2 over K=1024 for N=131072 rows of D=64; out = codewords.
//
//  k0 vq_prep:    LDS-staged: ET coalesced, ckseq = sequential f32 sum e^2
//                 (numpy axis-0 order), EB = bf16 hi/lo fragments of (-2e)
//                 (65 x 4096 B tiles). Zeroes flag counter.
//  k1 vq_mfma:    R16 skeleton (proven 73 us: L2-stream, named-slot depth-1
//                 pair prefetch, 4-wave blocks, grid 1024) with the ONE clean
//                 change: 2-PRODUCT scores (xh+xl)*eh -> 8 MFMA/tile (was 12).
//                 Clean A/B vs R16: does cutting MFMA work 33% move the wall?
//                 Score sigma ~9e-4; MARGIN 8e-3 (empirically passed R11/R12).
//  k2 vq_refineB: staged exact refine (R14/R16 proven), grid 2048 (16 chunks
//                 x 128 grps) to absorb n ~5-9k flags; atomicMin packed key.
//  k3 vq_refineC: wave per row: gather codeword, rewrite.

#define NROWS (32 * 64 * 64)   // 131072
#define DIM   64
#define KCB   1024
#define MARGIN 8e-3f

// ws layout (bytes):
#define ET_OFF    0           // float[1024*64] = 262144
#define CK_OFF    262144      // float[1088] pad -> 4352
#define EB_OFF    266496      // 65 tiles * 4096 B = 266240 (64 + 1 prefetch pad)
#define CNT_OFF   532736      // int (+pad)
#define RB_OFF    532992      // u64[16384] rowbest = 131072
#define LIST_OFF  664064      // int[16384] = 65536
#define LIST_CAP  16384

typedef float  f32x4 __attribute__((ext_vector_type(4)));
typedef short  s16x8 __attribute__((ext_vector_type(8)));

#define GLDS16(g, l) __builtin_amdgcn_global_load_lds( \
    (const __attribute__((address_space(1))) unsigned int*)(g), \
    (__attribute__((address_space(3))) unsigned int*)(l), 16, 0, 0)

static __device__ inline short bfb(float f) {   // f32 -> bf16 bits, RNE
    union { float f; unsigned u; } c{f};
    unsigned r = c.u + 0x7fffu + ((c.u >> 16) & 1u);
    return (short)(r >> 16);
}
static __device__ inline float bf2f(short b) {  // bf16 bits -> f32
    union { unsigned u; float f; } c{(unsigned)(unsigned short)b << 16};
    return c.f;
}

// Block b handles codebook cols [b*64, b*64+64). E-chunk staged to LDS once
// (coalesced); ET / ckseq / EB all derived from the exact LDS copies.
__global__ __launch_bounds__(256)
void vq_prep(const float* __restrict__ E,
             float* __restrict__ ET,
             float* __restrict__ ckseq,
             char* __restrict__ EB,
             int* __restrict__ count) {
    #pragma clang fp contract(off)
    __shared__ float es[DIM * 65];        // es[d][kk], pad-65 (16.6 KB)
    const int tid = threadIdx.x;
    const int b   = blockIdx.x;           // 0..15
    if (b == 0 && tid == 0) *count = 0;

    // stage: es[d][kk] = E[d*1024 + b*64 + kk]  (coalesced 64-float rows)
    #pragma unroll
    for (int i = 0; i < 16; ++i) {
        int idx = i * 256 + tid;          // 0..4095
        int d = idx >> 6, kk = idx & 63;
        es[d * 65 + kk] = E[d * KCB + b * 64 + kk];
    }
    __syncthreads();

    // ET coalesced from LDS transpose
    #pragma unroll
    for (int i = 0; i < 16; ++i) {
        int idx = i * 256 + tid;
        int nl = idx >> 6, d = idx & 63;
        ET[(size_t)(b * 64 + nl) * DIM + d] = es[d * 65 + nl];
    }

    // ckseq: sequential d=0..63 (numpy axis-0 order), exact E values
    if (tid < 64) {
        float c = 0.f;
        #pragma unroll
        for (int d = 0; d < DIM; ++d) {
            float v = es[d * 65 + tid];
            float q = v * v;
            c = c + q;
        }
        ckseq[b * 64 + tid] = c;
    }

    // EB tiles T = b*4 + ti (16 cols each). Parts: [0,1024) hi d0-31,
    // [1024,2048) hi d32-63, [2048,3072) lo d0-31, [3072,4096) lo d32-63.
    // Lane l = g*16+l15 holds d = blk*32 + g*8 + j; 16 B per lane.
    {
        int ti = tid >> 6, l = tid & 63;
        int g = l >> 4, l15 = l & 15;
        int kk = ti * 16 + l15;
        char* base = EB + (size_t)(b * 4 + ti) * 4096;
        #pragma unroll
        for (int p = 0; p < 4; ++p) {
            int dblk = p & 1, islo = p >> 1;
            s16x8 w;
            #pragma unroll
            for (int j = 0; j < 8; ++j) {
                float m = -2.f * es[(dblk * 32 + g * 8 + j) * 65 + kk];
                short h = bfb(m);
                w[j] = islo ? bfb(m - bf2f(h)) : h;
            }
            *(s16x8*)(base + (islo * 2048) + (dblk * 1024) + l * 16) = w;
        }
    }
}

// One 16-col tile: 4 MFMA C-chained per row-tile (2-product) + top-2.
#define COMPUTE_TILE(T, BH0, BH1, CCK)                                             \
    {                                                                              \
        f32x4 cin = {(CCK), (CCK), (CCK), (CCK)};                                  \
        int kc = (T) * 16 + l15;                                                   \
        _Pragma("unroll")                                                          \
        for (int rt = 0; rt < 2; ++rt) {                                           \
            f32x4 acc = cin;   /* C-in = ||e||^2 */                                \
            acc = __builtin_amdgcn_mfma_f32_16x16x32_bf16(aH[rt][0], BH0, acc, 0, 0, 0); \
            acc = __builtin_amdgcn_mfma_f32_16x16x32_bf16(aH[rt][1], BH1, acc, 0, 0, 0); \
            acc = __builtin_amdgcn_mfma_f32_16x16x32_bf16(aL[rt][0], BH0, acc, 0, 0, 0); \
            acc = __builtin_amdgcn_mfma_f32_16x16x32_bf16(aL[rt][1], BH1, acc, 0, 0, 0); \
            _Pragma("unroll")                                                      \
            for (int rr = 0; rr < 4; ++rr) {                                       \
                float s = acc[rr];            /* = ck - 2*(xh+xl).eh */            \
                int sl = rt * 4 + rr;                                              \
                bool cond = s < tb1[sl];                                           \
                tb2[sl] = __builtin_amdgcn_fmed3f(s, tb1[sl], tb2[sl]);            \
                tb1[sl] = fminf(tb1[sl], s);                                       \
                tix[sl] = cond ? kc : tix[sl];                                     \
            }                                                                      \
        }                                                                          \
    }

__global__ __launch_bounds__(256, 4)
__attribute__((amdgpu_waves_per_eu(4, 4)))
void vq_mfma(const float* __restrict__ x, const float* __restrict__ ck,
             const char* __restrict__ EB, const float* __restrict__ ET,
             float* __restrict__ out, int* __restrict__ count,
             int* __restrict__ list, unsigned long long* __restrict__ rowbest,
             int list_cap) {
    __shared__ float ckls[KCB + 16];     // +16: harmless pad-read at t=62
    __shared__ int idxbuf[128];

    const int tid  = threadIdx.x;
    const int lane = tid & 63;
    const int wv   = tid >> 6;            // wave 0..3
    const int l15  = lane & 15;
    const int g    = lane >> 4;           // 0..3
    const int rowbase = blockIdx.x * 128; // 128 rows per block, 32 per wave

    // ---- stage ck LUT once (only barrier in the kernel body) ----
    GLDS16(ck + wv * 256 + lane * 4, &ckls[wv * 256]);

    // ---- A fragments hi/lo: 2 rowtiles x 2 dblocks (32 VGPR persistent) ----
    s16x8 aH[2][2], aL[2][2];
    #pragma unroll
    for (int rt = 0; rt < 2; ++rt) {
        int row = rowbase + wv * 32 + rt * 16 + l15;
        const float* xp = x + (size_t)row * DIM + g * 8;
        #pragma unroll
        for (int s = 0; s < 2; ++s) {
            float val[8];
            float4 u = *(const float4*)(xp + s * 32);
            float4 v = *(const float4*)(xp + s * 32 + 4);
            val[0] = u.x; val[1] = u.y; val[2] = u.z; val[3] = u.w;
            val[4] = v.x; val[5] = v.y; val[6] = v.z; val[7] = v.w;
            s16x8 h, l;
            #pragma unroll
            for (int j = 0; j < 8; ++j) {
                short hb = bfb(val[j]);
                h[j] = hb;
                l[j] = bfb(val[j] - bf2f(hb));   // (xh+xl): A-side ~exact
            }
            aH[rt][s] = h;
            aL[rt][s] = l;
        }
    }
    __syncthreads();                      // ckls ready; no more block syncs

    // ---- top-2 state: slot = rt*4 + rr -> row rt*16 + g*4 + rr ----
    float tb1[8], tb2[8];
    int   tix[8];
    #pragma unroll
    for (int sl = 0; sl < 8; ++sl) { tb1[sl] = 1e30f; tb2[sl] = 1e30f; tix[sl] = 0; }

    // ---- barrier-free K-loop: per-wave B stream from L2, depth-1 prefetch --
    // (hi fragments only: 2-product scheme; lo halves of EB left unread)
    const char* ebp = EB + lane * 16;     // per-lane base
    s16x8 cH0 = *(const s16x8*)(ebp);
    s16x8 cH1 = *(const s16x8*)(ebp + 1024);
    float ckc = ckls[l15];

    #pragma unroll 1
    for (int t = 0; t < 64; t += 2) {
        // prefetch tile t+1 into n*
        const char* p1 = ebp + (size_t)(t + 1) * 4096;
        s16x8 nH0 = *(const s16x8*)(p1);
        s16x8 nH1 = *(const s16x8*)(p1 + 1024);
        float ckn = ckls[(t + 1) * 16 + l15];

        COMPUTE_TILE(t, cH0, cH1, ckc);

        // prefetch tile t+2 into c* (t=62 reads the pad tile; values unused)
        const char* p2 = ebp + (size_t)(t + 2) * 4096;
        cH0 = *(const s16x8*)(p2);
        cH1 = *(const s16x8*)(p2 + 1024);
        ckc = ckls[(t + 2) * 16 + l15];

        COMPUTE_TILE(t + 1, nH0, nH1, ckn);
    }

    // ---- merge top-2 across the 16 lanes of each g-group ----
    #pragma unroll
    for (int m = 1; m <= 8; m <<= 1) {
        #pragma unroll
        for (int sl = 0; sl < 8; ++sl) {
            float ob1 = __shfl_xor(tb1[sl], m);
            float ob2 = __shfl_xor(tb2[sl], m);
            int   oid = __shfl_xor(tix[sl], m);
            if (ob1 < tb1[sl] || (ob1 == tb1[sl] && oid < tix[sl])) {
                tb2[sl] = fminf(tb1[sl], ob2);
                tb1[sl] = ob1;
                tix[sl] = oid;
            } else {
                tb2[sl] = fminf(tb2[sl], ob1);
            }
        }
    }

    if (l15 == 0) {
        #pragma unroll
        for (int sl = 0; sl < 8; ++sl) {
            int rloc = wv * 32 + (sl >> 2) * 16 + g * 4 + (sl & 3);
            idxbuf[rloc] = tix[sl];
            if (tb2[sl] - tb1[sl] < MARGIN) {
                int slot = atomicAdd(count, 1);
                if (slot < list_cap) {
                    list[slot] = rowbase + rloc;
                    rowbest[slot] = ~0ull;      // init for refineB atomicMin
                }
            }
        }
    }
    __syncthreads();

    // ---- fused gather: out[rowbase + r][:] = ET[idx[r]][:] ----
    const float4* ET4 = (const float4*)ET;
    float4* out4 = (float4*)(out + (size_t)rowbase * DIM);
    #pragma unroll
    for (int p = 0; p < 8; ++p) {
        int f = p * 256 + tid;           // 0..2047
        int r = f >> 4, dq = f & 15;
        out4[f] = ET4[idxbuf[r] * 16 + dq];
    }
}

// STAGED exact refine (numpy-f32 chain semantics validated R2-R18).
// Grid 2048 = 16 chunks x 128 grps. Block stages E[0..63][c*64..+64) (16 KB)
// + ck into LDS once; waves run flagged rows' exact chains from LDS;
// atomicMin packed (ordbits(dist)<<32)|k into rowbest[slot].
__global__ __launch_bounds__(256)
void vq_refineB(const float* __restrict__ x, const float* __restrict__ E,
                const float* __restrict__ ckseq,
                const int* __restrict__ count, const int* __restrict__ list,
                unsigned long long* __restrict__ rowbest, int list_cap) {
    #pragma clang fp contract(off)
    __shared__ float es[DIM * 64];        // es[d][k] 16 KB
    __shared__ float cks[64];

    const int tid  = threadIdx.x;
    const int lane = tid & 63;
    const int wv   = tid >> 6;
    const int chunk = blockIdx.x & 15;
    const int grp   = blockIdx.x >> 4;    // 0..127

    #pragma unroll
    for (int i = 0; i < 16; ++i) {
        int d = i * 4 + wv;               // wave wv covers d = i*4+wv
        es[d * 64 + lane] = E[d * KCB + chunk * 64 + lane];
    }
    if (tid < 64) cks[tid] = ckseq[chunk * 64 + tid];
    __syncthreads();

    int n = *count;
    if (n > list_cap) n = list_cap;
    const int k = chunk * 64 + lane;

    for (int slot = grp * 4 + wv; slot < n; slot += 512) {
        int row = list[slot];
        const f32x4* z4 = (const f32x4*)(x + (size_t)row * DIM);

        // ||z||^2: numpy pairwise_sum n=64 (8-acc unrolled), validated order
        float r8[8];
        {
            f32x4 a = z4[0], b = z4[1];
            r8[0] = a.x * a.x; r8[1] = a.y * a.y; r8[2] = a.z * a.z; r8[3] = a.w * a.w;
            r8[4] = b.x * b.x; r8[5] = b.y * b.y; r8[6] = b.z * b.z; r8[7] = b.w * b.w;
        }
        #pragma unroll
        for (int gi = 1; gi < 8; ++gi) {
            f32x4 a = z4[gi * 2], b = z4[gi * 2 + 1];
            r8[0] = r8[0] + a.x * a.x; r8[1] = r8[1] + a.y * a.y;
            r8[2] = r8[2] + a.z * a.z; r8[3] = r8[3] + a.w * a.w;
            r8[4] = r8[4] + b.x * b.x; r8[5] = r8[5] + b.y * b.y;
            r8[6] = r8[6] + b.z * b.z; r8[7] = r8[7] + b.w * b.w;
        }
        float A = ((r8[0] + r8[1]) + (r8[2] + r8[3]))
                + ((r8[4] + r8[5]) + (r8[6] + r8[7]));

        float s = 0.f;                    // sequential fmaf over d (BLAS emu)
        #pragma unroll
        for (int q = 0; q < 16; ++q) {
            f32x4 zv = z4[q];
            s = fmaf(zv.x, es[(4 * q + 0) * 64 + lane], s);
            s = fmaf(zv.y, es[(4 * q + 1) * 64 + lane], s);
            s = fmaf(zv.z, es[(4 * q + 2) * 64 + lane], s);
            s = fmaf(zv.w, es[(4 * q + 3) * 64 + lane], s);
        }
        float t = A + cks[lane];
        float dist = t - 2.0f * s;

        unsigned u = __float_as_uint(dist);
        unsigned ord = u ^ ((u & 0x80000000u) ? 0xFFFFFFFFu : 0x80000000u);
        unsigned long long key = ((unsigned long long)ord << 32) | (unsigned)k;
        #pragma unroll
        for (int off = 32; off; off >>= 1) {
            unsigned long long ok = __shfl_xor(key, off);
            key = ok < key ? ok : key;
        }
        if (lane == 0) atomicMin(rowbest + slot, key);
    }
}

__global__ void vq_refineC(const float* __restrict__ ET,
                           float* __restrict__ out,
                           const int* __restrict__ count,
                           const int* __restrict__ list,
                           const unsigned long long* __restrict__ rowbest,
                           int list_cap) {
    int n = *count;
    if (n > list_cap) n = list_cap;
    int gw = (blockIdx.x * blockDim.x + threadIdx.x) >> 6;
    int lane = threadIdx.x & 63;
    int nw = (gridDim.x * blockDim.x) >> 6;
    for (int slot = gw; slot < n; slot += nw) {
        int row = list[slot];
        unsigned k = (unsigned)(rowbest[slot] & 0xFFFFFFFFu);
        out[(size_t)row * DIM + lane] = ET[(size_t)k * DIM + lane];
    }
}

extern "C" void kernel_launch(void* const* d_in, const int* in_sizes, int n_in,
                              void* d_out, int out_size, void* d_ws, size_t ws_size,
                              hipStream_t stream) {
    const float* x = (const float*)d_in[0];
    const float* E = (const float*)d_in[1];
    float* out = (float*)d_out;

    char* ws = (char*)d_ws;
    float* ET  = (float*)(ws + ET_OFF);
    float* ck  = (float*)(ws + CK_OFF);
    char*  EB  = ws + EB_OFF;
    int*   cnt = (int*)(ws + CNT_OFF);
    unsigned long long* rb = (unsigned long long*)(ws + RB_OFF);
    int*   lst = (int*)(ws + LIST_OFF);
    long long avail = (long long)ws_size - LIST_OFF;
    int list_cap = avail > 0 ? (int)(avail / 4) : 0;
    if (list_cap > LIST_CAP) list_cap = LIST_CAP;

    vq_prep<<<16, 256, 0, stream>>>(E, ET, ck, EB, cnt);
    vq_mfma<<<NROWS / 128, 256, 0, stream>>>(x, ck, EB, ET, out, cnt, lst, rb, list_cap);
    vq_refineB<<<2048, 256, 0, stream>>>(x, E, ck, cnt, lst, rb, list_cap);
    vq_refineC<<<256, 256, 0, stream>>>(ET, out, cnt, lst, rb, list_cap);
}

// Round 20
// 83.728 us; speedup vs baseline: 2.4814x; 2.4814x over previous
//
#include <hip/hip_runtime.h>
#include <hip/hip_bf16.h>

// VectorQuantiser: x [32,64,64,64] f32, embeddings [64,1024] f32.
// argmin_k ||z - e_k||^2 over K=1024 for N=131072 rows of D=64; out = codewords.
//
// FINAL (R16 assembly, best measured 84.2 us):
//  k0 vq_prep:    LDS-staged: ET coalesced, ckseq = sequential f32 sum e^2
//                 (numpy axis-0 order), EB = bf16 hi/lo fragments of (-2e).
//  k1 vq_mfma:    3-product hi/lo MFMA score = ck - 2*dot (err ~2e-6),
//                 barrier-free K-loop, named-slot depth-1 pair prefetch,
//                 4-wave blocks, grid 1024. MARGIN 1.5e-4 -> ~150 flags.
//                 (R19 A/B proved the 12 MFMA/tile are latency cover: cutting
//                 to 8 MFMA/tile raised wall 73->123 us. Local optimum.)
//  k2 vq_refineB: staged exact refine: block = (chunk, grp), E-chunk in LDS,
//                 exact numpy-f32 chains, atomicMin packed key.
//  k3 vq_refineC: wave per row: gather codeword, rewrite.

#define NROWS (32 * 64 * 64)   // 131072
#define DIM   64
#define KCB   1024
#define MARGIN 1.5e-4f

// ws layout (bytes):
#define ET_OFF    0           // float[1024*64] = 262144
#define CK_OFF    262144      // float[1088] pad -> 4352
#define EB_OFF    266496      // 65 tiles * 4096 B = 266240 (64 + 1 prefetch pad)
#define CNT_OFF   532736      // int (+pad)
#define RB_OFF    532992      // u64[8192] rowbest = 65536
#define LIST_OFF  598528      // int[8192] = 32768
#define LIST_CAP  8192

typedef float  f32x4 __attribute__((ext_vector_type(4)));
typedef short  s16x8 __attribute__((ext_vector_type(8)));

#define GLDS16(g, l) __builtin_amdgcn_global_load_lds( \
    (const __attribute__((address_space(1))) unsigned int*)(g), \
    (__attribute__((address_space(3))) unsigned int*)(l), 16, 0, 0)

static __device__ inline short bfb(float f) {   // f32 -> bf16 bits, RNE
    union { float f; unsigned u; } c{f};
    unsigned r = c.u + 0x7fffu + ((c.u >> 16) & 1u);
    return (short)(r >> 16);
}
static __device__ inline float bf2f(short b) {  // bf16 bits -> f32
    union { unsigned u; float f; } c{(unsigned)(unsigned short)b << 16};
    return c.f;
}

// Block b handles codebook cols [b*64, b*64+64). E-chunk staged to LDS once
// (coalesced); ET / ckseq / EB all derived from the exact LDS copies.
__global__ __launch_bounds__(256)
void vq_prep(const float* __restrict__ E,
             float* __restrict__ ET,
             float* __restrict__ ckseq,
             char* __restrict__ EB,
             int* __restrict__ count) {
    #pragma clang fp contract(off)
    __shared__ float es[DIM * 65];        // es[d][kk], pad-65 (16.6 KB)
    const int tid = threadIdx.x;
    const int b   = blockIdx.x;           // 0..15
    if (b == 0 && tid == 0) *count = 0;

    // stage: es[d][kk] = E[d*1024 + b*64 + kk]  (coalesced 64-float rows)
    #pragma unroll
    for (int i = 0; i < 16; ++i) {
        int idx = i * 256 + tid;          // 0..4095
        int d = idx >> 6, kk = idx & 63;
        es[d * 65 + kk] = E[d * KCB + b * 64 + kk];
    }
    __syncthreads();

    // ET[(b*64+nl)*64 + d] = es[d][nl]  (coalesced global stores)
    #pragma unroll
    for (int i = 0; i < 16; ++i) {
        int idx = i * 256 + tid;
        int nl = idx >> 6, d = idx & 63;
        ET[(size_t)(b * 64 + nl) * DIM + d] = es[d * 65 + nl];
    }

    // ckseq: sequential d=0..63 (numpy axis-0 order), exact E values
    if (tid < 64) {
        float c = 0.f;
        #pragma unroll
        for (int d = 0; d < DIM; ++d) {
            float v = es[d * 65 + tid];
            float q = v * v;
            c = c + q;
        }
        ckseq[b * 64 + tid] = c;
    }

    // EB tiles T = b*4 + ti (16 cols each). Parts: [0,1024) hi d0-31,
    // [1024,2048) hi d32-63, [2048,3072) lo d0-31, [3072,4096) lo d32-63.
    // Lane l = g*16+l15 holds d = blk*32 + g*8 + j; 16 B per lane.
    {
        int ti = tid >> 6, l = tid & 63;
        int g = l >> 4, l15 = l & 15;
        int kk = ti * 16 + l15;
        char* base = EB + (size_t)(b * 4 + ti) * 4096;
        #pragma unroll
        for (int p = 0; p < 4; ++p) {
            int dblk = p & 1, islo = p >> 1;
            s16x8 w;
            #pragma unroll
            for (int j = 0; j < 8; ++j) {
                float m = -2.f * es[(dblk * 32 + g * 8 + j) * 65 + kk];
                short h = bfb(m);
                w[j] = islo ? bfb(m - bf2f(h)) : h;
            }
            *(s16x8*)(base + (islo * 2048) + (dblk * 1024) + l * 16) = w;
        }
    }
}

// One 16-col tile: 6 MFMA C-chained per row-tile + branchless top-2.
#define COMPUTE_TILE(T, BH0, BH1, BL0, BL1, CCK)                                   \
    {                                                                              \
        f32x4 cin = {(CCK), (CCK), (CCK), (CCK)};                                  \
        int kc = (T) * 16 + l15;                                                   \
        _Pragma("unroll")                                                          \
        for (int rt = 0; rt < 2; ++rt) {                                           \
            f32x4 acc = cin;   /* C-in = ||e||^2 */                                \
            acc = __builtin_amdgcn_mfma_f32_16x16x32_bf16(aH[rt][0], BH0, acc, 0, 0, 0); \
            acc = __builtin_amdgcn_mfma_f32_16x16x32_bf16(aH[rt][1], BH1, acc, 0, 0, 0); \
            acc = __builtin_amdgcn_mfma_f32_16x16x32_bf16(aL[rt][0], BH0, acc, 0, 0, 0); \
            acc = __builtin_amdgcn_mfma_f32_16x16x32_bf16(aL[rt][1], BH1, acc, 0, 0, 0); \
            acc = __builtin_amdgcn_mfma_f32_16x16x32_bf16(aH[rt][0], BL0, acc, 0, 0, 0); \
            acc = __builtin_amdgcn_mfma_f32_16x16x32_bf16(aH[rt][1], BL1, acc, 0, 0, 0); \
            _Pragma("unroll")                                                      \
            for (int rr = 0; rr < 4; ++rr) {                                       \
                float s = acc[rr];            /* = ck - 2*dot (hi/lo accurate) */  \
                int sl = rt * 4 + rr;                                              \
                bool cond = s < tb1[sl];                                           \
                tb2[sl] = __builtin_amdgcn_fmed3f(s, tb1[sl], tb2[sl]);            \
                tb1[sl] = fminf(tb1[sl], s);                                       \
                tix[sl] = cond ? kc : tix[sl];                                     \
            }                                                                      \
        }                                                                          \
    }

__global__ __launch_bounds__(256, 4)
__attribute__((amdgpu_waves_per_eu(4, 4)))
void vq_mfma(const float* __restrict__ x, const float* __restrict__ ck,
             const char* __restrict__ EB, const float* __restrict__ ET,
             float* __restrict__ out, int* __restrict__ count,
             int* __restrict__ list, unsigned long long* __restrict__ rowbest,
             int list_cap) {
    __shared__ float ckls[KCB + 16];     // +16: harmless pad-read at t=62
    __shared__ int idxbuf[128];

    const int tid  = threadIdx.x;
    const int lane = tid & 63;
    const int wv   = tid >> 6;            // wave 0..3
    const int l15  = lane & 15;
    const int g    = lane >> 4;           // 0..3
    const int rowbase = blockIdx.x * 128; // 128 rows per block, 32 per wave

    // ---- stage ck LUT once (only barrier in the kernel body) ----
    GLDS16(ck + wv * 256 + lane * 4, &ckls[wv * 256]);

    // ---- A fragments hi/lo: 2 rowtiles x 2 dblocks (32 VGPR persistent) ----
    s16x8 aH[2][2], aL[2][2];
    #pragma unroll
    for (int rt = 0; rt < 2; ++rt) {
        int row = rowbase + wv * 32 + rt * 16 + l15;
        const float* xp = x + (size_t)row * DIM + g * 8;
        #pragma unroll
        for (int s = 0; s < 2; ++s) {
            float val[8];
            float4 u = *(const float4*)(xp + s * 32);
            float4 v = *(const float4*)(xp + s * 32 + 4);
            val[0] = u.x; val[1] = u.y; val[2] = u.z; val[3] = u.w;
            val[4] = v.x; val[5] = v.y; val[6] = v.z; val[7] = v.w;
            s16x8 h, l;
            #pragma unroll
            for (int j = 0; j < 8; ++j) {
                short hb = bfb(val[j]);
                h[j] = hb;
                l[j] = bfb(val[j] - bf2f(hb));
            }
            aH[rt][s] = h;
            aL[rt][s] = l;
        }
    }
    __syncthreads();                      // ckls ready; no more block syncs

    // ---- top-2 state: slot = rt*4 + rr -> row rt*16 + g*4 + rr ----
    float tb1[8], tb2[8];
    int   tix[8];
    #pragma unroll
    for (int sl = 0; sl < 8; ++sl) { tb1[sl] = 1e30f; tb2[sl] = 1e30f; tix[sl] = 0; }

    // ---- barrier-free K-loop: per-wave B stream from L2, depth-1 prefetch --
    const char* ebp = EB + lane * 16;     // per-lane base
    s16x8 cH0 = *(const s16x8*)(ebp);
    s16x8 cH1 = *(const s16x8*)(ebp + 1024);
    s16x8 cL0 = *(const s16x8*)(ebp + 2048);
    s16x8 cL1 = *(const s16x8*)(ebp + 3072);
    float ckc = ckls[l15];

    #pragma unroll 1
    for (int t = 0; t < 64; t += 2) {
        // prefetch tile t+1 into n*
        const char* p1 = ebp + (size_t)(t + 1) * 4096;
        s16x8 nH0 = *(const s16x8*)(p1);
        s16x8 nH1 = *(const s16x8*)(p1 + 1024);
        s16x8 nL0 = *(const s16x8*)(p1 + 2048);
        s16x8 nL1 = *(const s16x8*)(p1 + 3072);
        float ckn = ckls[(t + 1) * 16 + l15];

        COMPUTE_TILE(t, cH0, cH1, cL0, cL1, ckc);

        // prefetch tile t+2 into c* (t=62 reads the pad tile; values unused)
        const char* p2 = ebp + (size_t)(t + 2) * 4096;
        cH0 = *(const s16x8*)(p2);
        cH1 = *(const s16x8*)(p2 + 1024);
        cL0 = *(const s16x8*)(p2 + 2048);
        cL1 = *(const s16x8*)(p2 + 3072);
        ckc = ckls[(t + 2) * 16 + l15];

        COMPUTE_TILE(t + 1, nH0, nH1, nL0, nL1, ckn);
    }

    // ---- merge top-2 across the 16 lanes of each g-group ----
    #pragma unroll
    for (int m = 1; m <= 8; m <<= 1) {
        #pragma unroll
        for (int sl = 0; sl < 8; ++sl) {
            float ob1 = __shfl_xor(tb1[sl], m);
            float ob2 = __shfl_xor(tb2[sl], m);
            int   oid = __shfl_xor(tix[sl], m);
            if (ob1 < tb1[sl] || (ob1 == tb1[sl] && oid < tix[sl])) {
                tb2[sl] = fminf(tb1[sl], ob2);
                tb1[sl] = ob1;
                tix[sl] = oid;
            } else {
                tb2[sl] = fminf(tb2[sl], ob1);
            }
        }
    }

    if (l15 == 0) {
        #pragma unroll
        for (int sl = 0; sl < 8; ++sl) {
            int rloc = wv * 32 + (sl >> 2) * 16 + g * 4 + (sl & 3);
            idxbuf[rloc] = tix[sl];
            if (tb2[sl] - tb1[sl] < MARGIN) {
                int slot = atomicAdd(count, 1);
                if (slot < list_cap) {
                    list[slot] = rowbase + rloc;
                    rowbest[slot] = ~0ull;      // init for refineB atomicMin
                }
            }
        }
    }
    __syncthreads();

    // ---- fused gather: out[rowbase + r][:] = ET[idx[r]][:] ----
    const float4* ET4 = (const float4*)ET;
    float4* out4 = (float4*)(out + (size_t)rowbase * DIM);
    #pragma unroll
    for (int p = 0; p < 8; ++p) {
        int f = p * 256 + tid;           // 0..2047
        int r = f >> 4, dq = f & 15;
        out4[f] = ET4[idxbuf[r] * 16 + dq];
    }
}

// STAGED exact refine (numpy-f32 chain semantics validated R2-R19).
// Block = (chunk c, group): stages E[0..63][c*64..c*64+63] (16 KB) + ck chunk
// into LDS once; each wave then processes flagged rows for this chunk:
// lane = k-in-chunk, sequential fmaf over d from LDS (2 lanes/bank = free),
// pack (ordbits(dist)<<32)|k, wave-reduce min, atomicMin into rowbest[slot].
__global__ __launch_bounds__(256)
void vq_refineB(const float* __restrict__ x, const float* __restrict__ E,
                const float* __restrict__ ckseq,
                const int* __restrict__ count, const int* __restrict__ list,
                unsigned long long* __restrict__ rowbest, int list_cap) {
    #pragma clang fp contract(off)
    __shared__ float es[DIM * 64];        // es[d][k] 16 KB
    __shared__ float cks[64];

    const int tid  = threadIdx.x;
    const int lane = tid & 63;
    const int wv   = tid >> 6;
    const int chunk = blockIdx.x & 15;
    const int grp   = blockIdx.x >> 4;    // 0..31

    // stage E chunk: es[d][k] = E[d*1024 + chunk*64 + k]
    #pragma unroll
    for (int i = 0; i < 16; ++i) {
        int d = i * 4 + wv;               // wave wv covers d = i*4+wv
        es[d * 64 + lane] = E[d * KCB + chunk * 64 + lane];
    }
    if (tid < 64) cks[tid] = ckseq[chunk * 64 + tid];
    __syncthreads();

    int n = *count;
    if (n > list_cap) n = list_cap;
    const int k = chunk * 64 + lane;

    for (int slot = grp * 4 + wv; slot < n; slot += 128) {
        int row = list[slot];
        const f32x4* z4 = (const f32x4*)(x + (size_t)row * DIM);

        // ||z||^2: numpy pairwise_sum n=64 (8-acc unrolled), validated order
        float r8[8];
        {
            f32x4 a = z4[0], b = z4[1];
            r8[0] = a.x * a.x; r8[1] = a.y * a.y; r8[2] = a.z * a.z; r8[3] = a.w * a.w;
            r8[4] = b.x * b.x; r8[5] = b.y * b.y; r8[6] = b.z * b.z; r8[7] = b.w * b.w;
        }
        #pragma unroll
        for (int gi = 1; gi < 8; ++gi) {
            f32x4 a = z4[gi * 2], b = z4[gi * 2 + 1];
            r8[0] = r8[0] + a.x * a.x; r8[1] = r8[1] + a.y * a.y;
            r8[2] = r8[2] + a.z * a.z; r8[3] = r8[3] + a.w * a.w;
            r8[4] = r8[4] + b.x * b.x; r8[5] = r8[5] + b.y * b.y;
            r8[6] = r8[6] + b.z * b.z; r8[7] = r8[7] + b.w * b.w;
        }
        float A = ((r8[0] + r8[1]) + (r8[2] + r8[3]))
                + ((r8[4] + r8[5]) + (r8[6] + r8[7]));

        float s = 0.f;                    // sequential fmaf over d (BLAS emu)
        #pragma unroll
        for (int q = 0; q < 16; ++q) {
            f32x4 zv = z4[q];
            s = fmaf(zv.x, es[(4 * q + 0) * 64 + lane], s);
            s = fmaf(zv.y, es[(4 * q + 1) * 64 + lane], s);
            s = fmaf(zv.z, es[(4 * q + 2) * 64 + lane], s);
            s = fmaf(zv.w, es[(4 * q + 3) * 64 + lane], s);
        }
        float t = A + cks[lane];
        float dist = t - 2.0f * s;

        unsigned u = __float_as_uint(dist);
        unsigned ord = u ^ ((u & 0x80000000u) ? 0xFFFFFFFFu : 0x80000000u);
        unsigned long long key = ((unsigned long long)ord << 32) | (unsigned)k;
        #pragma unroll
        for (int off = 32; off; off >>= 1) {
            unsigned long long ok = __shfl_xor(key, off);
            key = ok < key ? ok : key;
        }
        if (lane == 0) atomicMin(rowbest + slot, key);
    }
}

__global__ void vq_refineC(const float* __restrict__ ET,
                           float* __restrict__ out,
                           const int* __restrict__ count,
                           const int* __restrict__ list,
                           const unsigned long long* __restrict__ rowbest,
                           int list_cap) {
    int n = *count;
    if (n > list_cap) n = list_cap;
    int gw = (blockIdx.x * blockDim.x + threadIdx.x) >> 6;
    int lane = threadIdx.x & 63;
    int nw = (gridDim.x * blockDim.x) >> 6;
    for (int slot = gw; slot < n; slot += nw) {
        int row = list[slot];
        unsigned k = (unsigned)(rowbest[slot] & 0xFFFFFFFFu);
        out[(size_t)row * DIM + lane] = ET[(size_t)k * DIM + lane];
    }
}

extern "C" void kernel_launch(void* const* d_in, const int* in_sizes, int n_in,
                              void* d_out, int out_size, void* d_ws, size_t ws_size,
                              hipStream_t stream) {
    const float* x = (const float*)d_in[0];
    const float* E = (const float*)d_in[1];
    float* out = (float*)d_out;

    char* ws = (char*)d_ws;
    float* ET  = (float*)(ws + ET_OFF);
    float* ck  = (float*)(ws + CK_OFF);
    char*  EB  = ws + EB_OFF;
    int*   cnt = (int*)(ws + CNT_OFF);
    unsigned long long* rb = (unsigned long long*)(ws + RB_OFF);
    int*   lst = (int*)(ws + LIST_OFF);
    long long avail = (long long)ws_size - LIST_OFF;
    int list_cap = avail > 0 ? (int)(avail / 4) : 0;
    if (list_cap > LIST_CAP) list_cap = LIST_CAP;

    vq_prep<<<16, 256, 0, stream>>>(E, ET, ck, EB, cnt);
    vq_mfma<<<NROWS / 128, 256, 0, stream>>>(x, ck, EB, ET, out, cnt, lst, rb, list_cap);
    vq_refineB<<<512, 256, 0, stream>>>(x, E, ck, cnt, lst, rb, list_cap);
    vq_refineC<<<128, 256, 0, stream>>>(ET, out, cnt, lst, rb, list_cap);
}